// Round 6
// 2558.047 us; speedup vs baseline: 1.0999x; 1.0999x over previous
//
#include <hip/hip_runtime.h>
#include <stdint.h>

// LSTM: V=50000, D=256, H=512, B=64, T=512. out = stack([c_final, h_final]) fp32 [2,64,512]
//
// R9: wave-autonomous refactor of the PROVEN R3 kernel. Identical resource
//     envelope (coop 64 WG x 256 thr, 48 KB LDS, ~120 VGPR) -- only the
//     intra-WG organization changes:
//   - R3's 4 gates of (b,u) live in lanes u / u+8 of ONE wave (acc0 = i,j;
//     acc1 = f,o). One __shfl_xor(...,8) pair replaces the whole gsc/hst LDS
//     epilogue machinery => ZERO __syncthreads in the step loop.
//   - Each wave owns 16 batch rows end-to-end: x-MFMAs -> poll its own 64
//     producer-wave flags -> load its 16 h rows (sc0 sc1) -> h-MFMAs ->
//     in-wave cell update -> store h from registers -> drain -> post per-wave
//     flag. Waves drift independently; only true data deps couple them.
//   - Depth-2 ping-pong safe at wave granularity: wave W posting flag t
//     implies its h(t-1) reads completed (h(t) values are data-dependent on
//     them), so overwriting buf[t&1] after observing all flags >= t is safe.
//   - t=0 skips poll+h-part (h_0 = 0): no dependence on h-buffer init.

#define NWG     64
#define NTHR    256
#define TSTEPS  512
#define BATCH   64
#define EDIM    256
#define HID     512
#define GCOLS   2048

typedef __attribute__((ext_vector_type(8))) short short8;
typedef __attribute__((ext_vector_type(4))) float f32x4;

// ws layout:
//   256    : flags, 64 WG x 4 wave-flags x 32 u32 (128 B apart)   32 KB
//   33280  : hb0 [64][512] bf16 (64 KB)
//   98816  : hb1 [64][512] bf16 (64 KB)
//   164352 : xb bf16 [t][b][d] (16.8 MB)

__device__ __forceinline__ unsigned short f2bf(float f) {
  unsigned u = __float_as_uint(f);
  unsigned r = (u + 0x7FFFu + ((u >> 16) & 1u)) >> 16;  // RNE
  return (unsigned short)r;
}
__device__ __forceinline__ float sigf(float x) {
  x = fminf(fmaxf(x, -30.0f), 30.0f);
  return 1.0f / (1.0f + __expf(-x));
}
__device__ __forceinline__ float tanh_fast(float x) {
  x = fminf(fmaxf(x, -15.0f), 15.0f);
  float e = __expf(-2.0f * x);
  return (1.0f - e) / (1.0f + e);
}
__device__ __forceinline__ void lstm_cell(float gi, float gj, float gf, float go,
                                          int t, int nw, float& c, float& h) {
  float cn = sigf(gf + 1.0f) * c + sigf(gi) * tanh_fast(gj);  // FORGET_BIAS=1
  float hn = sigf(go) * tanh_fast(cn);
  if (t < nw) { c = cn; h = hn; }      // static_rnn: copy state through past end
}

__global__ void init_ws(unsigned* ws, int nwords) {
  int i = blockIdx.x * 256 + threadIdx.x;
  if (i < nwords) ws[i] = 0u;
}

// one block per (t,b): gather embedding row, convert to bf16, write xb[t][b][:]
__global__ void embed_k(const int* __restrict__ widx, const float* __restrict__ Wemb,
                        unsigned short* __restrict__ xb) {
  int tb = blockIdx.x;                 // t*64 + b
  int t = tb >> 6, b = tb & 63;
  int wi = widx[b * TSTEPS + t];       // word_indices is [B,T]
  const float* src = Wemb + (size_t)wi * EDIM + threadIdx.x * 4;
  float4 v = *(const float4*)src;
  ushort4 o;
  o.x = f2bf(v.x); o.y = f2bf(v.y); o.z = f2bf(v.z); o.w = f2bf(v.w);
  *(ushort4*)(xb + (size_t)tb * EDIM + threadIdx.x * 4) = o;
}

__launch_bounds__(NTHR, 1)
__global__ void lstm_persist(const int* __restrict__ num_words,
                             const int* __restrict__ widx,
                             const float* __restrict__ Wemb,
                             const float* __restrict__ Wk,
                             const float* __restrict__ bias,
                             const unsigned short* __restrict__ xb,
                             unsigned short* __restrict__ hb0,
                             unsigned short* __restrict__ hb1,
                             unsigned* flags,
                             float* __restrict__ out,
                             int has_xb)
{
  // B-fragment-ordered W strip (R3-proven layout): frag q = (ntile*24 + kk)*64 + lane:
  //   B[k = kk*32 + (lane>>4)*8 + j][n = ntile*16 + (lane&15)], n -> gcol = (n>>3)*512 + u0 + (n&7)
  __shared__ alignas(16) short Wlds[24576];      // 48 KB

  const int tid  = threadIdx.x;
  const int lane = tid & 63;
  const int wv   = tid >> 6;
  const int u0   = blockIdx.x * 8;               // this WG's hidden units u0..u0+7

  for (int q = tid; q < 3072; q += NTHR) {
    int lq = q & 63;
    int kkn = q >> 6;                            // 0..47
    int nt = (kkn >= 24) ? 1 : 0;
    int kk = kkn - nt * 24;
    int kbase = kk * 32 + ((lq >> 4) << 3);
    int nn = (nt << 4) + (lq & 15);
    int gcol = ((nn >> 3) << 9) + u0 + (nn & 7); // gate g -> cols g*512 + unit
    short8 v;
#pragma unroll
    for (int j = 0; j < 8; ++j)
      v[j] = (short)f2bf(Wk[(size_t)(kbase + j) * GCOLS + gcol]);
    *(short8*)&Wlds[q * 8] = v;
  }

  // MFMA geometry: wave wv owns batches wv*16..+15; 2 N-tiles (32 gate cols).
  const int n   = lane & 15;                     // C col: gate pair + unit
  const int q4  = lane >> 4;                     // row quarter
  const int bb  = wv * 16 + n;                   // A-row (batch) this lane loads
  const int kq  = q4 << 3;                       // k sub-offset 0/8/16/24
  const int un  = n & 7;                         // unit within WG
  const bool lo = (n < 8);                       // lanes holding gates (i,f); hi = (j,o)

  // per-lane constants
  float bias_g[4];
#pragma unroll
  for (int g = 0; g < 4; ++g) bias_g[g] = bias[g * HID + u0 + un];
  int nw_r[4];
#pragma unroll
  for (int r = 0; r < 4; ++r) nw_r[r] = num_words[wv * 16 + q4 * 4 + r];

  float c_r[4] = {0.f, 0.f, 0.f, 0.f};
  float h_r[4] = {0.f, 0.f, 0.f, 0.f};

  unsigned* myflag = flags + ((blockIdx.x << 2) + wv) * 32;     // this wave's flag
  const unsigned* fp = flags + ((lane << 2) + wv) * 32;         // lane l polls WG l, wave wv

  unsigned short* hb[2] = {hb0, hb1};

  __syncthreads();                               // Wlds ready (setup only)

  for (int t = 0; t < TSTEPS; ++t) {
    f32x4 acc0 = {0.f, 0.f, 0.f, 0.f};
    f32x4 acc1 = {0.f, 0.f, 0.f, 0.f};

    // ---- x part (k=0..255): independent of recurrence, runs before the wait ----
    if (has_xb) {
      const unsigned short* xrow = xb + ((size_t)t * BATCH + bb) * EDIM + kq;
#pragma unroll
      for (int kk = 0; kk < 8; ++kk) {
        short8 a  = __builtin_bit_cast(short8, *(const uint4*)(xrow + kk * 32));
        short8 w0 = *(const short8*)&Wlds[((kk)      * 64 + lane) * 8];
        short8 w1 = *(const short8*)&Wlds[((24 + kk) * 64 + lane) * 8];
        acc0 = __builtin_amdgcn_mfma_f32_16x16x32_bf16(a, w0, acc0, 0, 0, 0);
        acc1 = __builtin_amdgcn_mfma_f32_16x16x32_bf16(a, w1, acc1, 0, 0, 0);
      }
    } else {
      int wi = widx[bb * TSTEPS + t];
      const float* erow = Wemb + (size_t)wi * EDIM + kq;
#pragma unroll
      for (int kk = 0; kk < 8; ++kk) {
        float4 f0 = *(const float4*)(erow + kk * 32);
        float4 f1 = *(const float4*)(erow + kk * 32 + 4);
        short8 a;
        a[0] = (short)f2bf(f0.x); a[1] = (short)f2bf(f0.y);
        a[2] = (short)f2bf(f0.z); a[3] = (short)f2bf(f0.w);
        a[4] = (short)f2bf(f1.x); a[5] = (short)f2bf(f1.y);
        a[6] = (short)f2bf(f1.z); a[7] = (short)f2bf(f1.w);
        short8 w0 = *(const short8*)&Wlds[((kk)      * 64 + lane) * 8];
        short8 w1 = *(const short8*)&Wlds[((24 + kk) * 64 + lane) * 8];
        acc0 = __builtin_amdgcn_mfma_f32_16x16x32_bf16(a, w0, acc0, 0, 0, 0);
        acc1 = __builtin_amdgcn_mfma_f32_16x16x32_bf16(a, w1, acc1, 0, 0, 0);
      }
    }

    if (t > 0) {
      // ---- poll this wave's 64 producer waves (wave wv of every WG) ----
      const unsigned tgt = (unsigned)t;
      for (;;) {
        unsigned v;
        asm volatile("global_load_dword %0, %1, off sc0 sc1\n\t"
                     "s_waitcnt vmcnt(0)" : "=v"(v) : "v"(fp));
        if (__ballot(v >= tgt) == ~0ull) break;
      }

      // ---- h part (k=256..767): batched LLC loads, one drain, then MFMAs ----
      const unsigned short* hr = hb[t & 1] + bb * HID + kq;
      uint4 av[16];
#pragma unroll
      for (int kk = 0; kk < 16; ++kk)
        asm volatile("global_load_dwordx4 %0, %1, off sc0 sc1"
                     : "=v"(av[kk]) : "v"(hr + kk * 32));
      asm volatile("s_waitcnt vmcnt(0)" ::: "memory");
      __builtin_amdgcn_sched_barrier(0);         // keep MFMAs below the drain
#pragma unroll
      for (int kk = 0; kk < 16; ++kk) {
        short8 a  = __builtin_bit_cast(short8, av[kk]);
        short8 w0 = *(const short8*)&Wlds[((8 + kk)  * 64 + lane) * 8];
        short8 w1 = *(const short8*)&Wlds[((32 + kk) * 64 + lane) * 8];
        acc0 = __builtin_amdgcn_mfma_f32_16x16x32_bf16(a, w0, acc0, 0, 0, 0);
        acc1 = __builtin_amdgcn_mfma_f32_16x16x32_bf16(a, w1, acc1, 0, 0, 0);
      }
    }
    // (t==0: h_0 = 0 contributes nothing -- skip poll and h part)

    // ---- in-wave epilogue: gates (i,j) in acc0 lanes n/n+8, (f,o) in acc1 ----
#pragma unroll
    for (int r = 0; r < 4; ++r) {
      float a0o = acc0[r], a1o = acc1[r];
      float a0x = __shfl_xor(a0o, 8);
      float a1x = __shfl_xor(a1o, 8);
      float gi = lo ? a0o : a0x;
      float gj = lo ? a0x : a0o;
      float gf = lo ? a1o : a1x;
      float go = lo ? a1x : a1o;
      lstm_cell(gi + bias_g[0], gj + bias_g[1], gf + bias_g[2], go + bias_g[3],
                t, nw_r[r], c_r[r], h_r[r]);
    }

    // ---- publish h(t+1): direct register stores, drain, post wave flag ----
    if (t + 1 < TSTEPS) {
      unsigned short* hw = hb[(t + 1) & 1];
      if (lo) {                                  // lanes n<8: one (b,u) per row
#pragma unroll
        for (int r = 0; r < 4; ++r) {
          unsigned short* dst = hw + (size_t)(wv * 16 + q4 * 4 + r) * HID + u0 + un;
          unsigned hv = (unsigned)f2bf(h_r[r]);
          asm volatile("global_store_short %0, %1, off sc0 sc1"
                       :: "v"(dst), "v"(hv) : "memory");
        }
      }
      asm volatile("s_waitcnt vmcnt(0)" ::: "memory");   // wave-wide drain
      if (lane == 0) {
        unsigned fv = (unsigned)(t + 1);
        asm volatile("global_store_dword %0, %1, off sc0 sc1"
                     :: "v"(myflag), "v"(fv) : "memory");
      }
    }
  }

  // ---- final state: out[0][b][h]=c, out[1][b][h]=h ----
  if (lo) {
#pragma unroll
    for (int r = 0; r < 4; ++r) {
      int b = wv * 16 + q4 * 4 + r;
      out[b * HID + u0 + un]                   = c_r[r];
      out[BATCH * HID + b * HID + u0 + un]     = h_r[r];
    }
  }
}

extern "C" void kernel_launch(void* const* d_in, const int* in_sizes, int n_in,
                              void* d_out, int out_size, void* d_ws, size_t ws_size,
                              hipStream_t stream) {
  const int*   widx = (const int*)d_in[0];
  const int*   nw   = (const int*)d_in[1];
  const float* Wemb = (const float*)d_in[2];
  const float* Wk   = (const float*)d_in[3];
  const float* bias = (const float*)d_in[4];
  float* out = (float*)d_out;
  char* ws = (char*)d_ws;

  unsigned* flags       = (unsigned*)(ws + 256);
  unsigned short* hb0   = (unsigned short*)(ws + 33280);
  unsigned short* hb1   = (unsigned short*)(ws + 98816);
  unsigned short* xb    = (unsigned short*)(ws + 164352);

  size_t need = 164352ull + (size_t)TSTEPS * BATCH * EDIM * 2;
  int has_xb = (ws_size >= need) ? 1 : 0;

  const int init_words = 164352 / 4;  // flags + both h buffers
  init_ws<<<(init_words + 255) / 256, 256, 0, stream>>>((unsigned*)ws, init_words);
  if (has_xb)
    embed_k<<<TSTEPS * BATCH, 64, 0, stream>>>(widx, Wemb, xb);

  void* args[] = {(void*)&nw, (void*)&widx, (void*)&Wemb, (void*)&Wk, (void*)&bias,
                  (void*)&xb, (void*)&hb0, (void*)&hb1, (void*)&flags,
                  (void*)&out, (void*)&has_xb};
  hipLaunchCooperativeKernel((void*)lstm_persist, dim3(NWG), dim3(NTHR), args, 0, stream);
}

// Round 8
// 2404.945 us; speedup vs baseline: 1.1700x; 1.0637x over previous
//
#include <hip/hip_runtime.h>
#include <stdint.h>

// LSTM: V=50000, D=256, H=512, B=64, T=512. out = stack([c_final, h_final]) fp32 [2,64,512]
//
// R11: R10's plan with the compile fix + counted-vmcnt store-ack.
//   - R10 failed: asm input constraint "v" on uint4 (struct) unsupported. The
//     packed h-store now uses 64 lanes x global_store_dword (scalar inputs OK,
//     one coalesced 256B transaction per wave, same pattern R3 proved).
//   - Pipeline: poll -> issue h-loads -> x-MFMAs from PREFETCHED regs (overlap
//     h RT) -> drain -> h-MFMAs -> epilogue -> issue h-stores -> issue x(t+1)
//     prefetch -> s_waitcnt vmcnt(16) [8 if xb]: store (oldest of 17) proven
//     retired, gather loads STAY IN FLIGHT -> flag. Gather RT hides under
//     store-ack RT + next poll RT.
//   - Everything else identical to R9 (PASSED): coop 64x256, 48KB LDS, wave-
//     autonomous protocol, per-wave flags, shfl_xor epilogue.

#define NWG     64
#define NTHR    256
#define TSTEPS  512
#define BATCH   64
#define EDIM    256
#define HID     512
#define GCOLS   2048

typedef __attribute__((ext_vector_type(8))) short short8;
typedef __attribute__((ext_vector_type(4))) float f32x4;

// ws layout:
//   256    : flags, 64 WG x 4 wave-flags x 32 u32 (128 B apart)   32 KB
//   33280  : hb0 [64][512] bf16 (64 KB)
//   98816  : hb1 [64][512] bf16 (64 KB)
//   164352 : xb bf16 [t][b][d] (16.8 MB)  -- only if ws_size permits

__device__ __forceinline__ unsigned short f2bf(float f) {
  unsigned u = __float_as_uint(f);
  unsigned r = (u + 0x7FFFu + ((u >> 16) & 1u)) >> 16;  // RNE
  return (unsigned short)r;
}
__device__ __forceinline__ float sigf(float x) {
  x = fminf(fmaxf(x, -30.0f), 30.0f);
  return 1.0f / (1.0f + __expf(-x));
}
__device__ __forceinline__ float tanh_fast(float x) {
  x = fminf(fmaxf(x, -15.0f), 15.0f);
  float e = __expf(-2.0f * x);
  return (1.0f - e) / (1.0f + e);
}
__device__ __forceinline__ void lstm_cell(float gi, float gj, float gf, float go,
                                          int t, int nw, float& c, float& h) {
  float cn = sigf(gf + 1.0f) * c + sigf(gi) * tanh_fast(gj);  // FORGET_BIAS=1
  float hn = sigf(go) * tanh_fast(cn);
  if (t < nw) { c = cn; h = hn; }      // static_rnn: copy state through past end
}

__global__ void init_ws(unsigned* ws, int nwords) {
  int i = blockIdx.x * 256 + threadIdx.x;
  if (i < nwords) ws[i] = 0u;
}

// one block per (t,b): gather embedding row, convert to bf16, write xb[t][b][:]
__global__ void embed_k(const int* __restrict__ widx, const float* __restrict__ Wemb,
                        unsigned short* __restrict__ xb) {
  int tb = blockIdx.x;                 // t*64 + b
  int t = tb >> 6, b = tb & 63;
  int wi = widx[b * TSTEPS + t];       // word_indices is [B,T]
  const float* src = Wemb + (size_t)wi * EDIM + threadIdx.x * 4;
  float4 v = *(const float4*)src;
  ushort4 o;
  o.x = f2bf(v.x); o.y = f2bf(v.y); o.z = f2bf(v.z); o.w = f2bf(v.w);
  *(ushort4*)(xb + (size_t)tb * EDIM + threadIdx.x * 4) = o;
}

__launch_bounds__(NTHR, 1)
__global__ void lstm_persist(const int* __restrict__ num_words,
                             const int* __restrict__ widx,
                             const float* __restrict__ Wemb,
                             const float* __restrict__ Wk,
                             const float* __restrict__ bias,
                             const unsigned short* __restrict__ xb,
                             unsigned short* __restrict__ hb0,
                             unsigned short* __restrict__ hb1,
                             unsigned* flags,
                             float* __restrict__ out,
                             int has_xb)
{
  // B-fragment-ordered W strip (R3/R9-proven layout): frag q = (ntile*24 + kk)*64 + lane:
  //   B[k = kk*32 + (lane>>4)*8 + j][n = ntile*16 + (lane&15)], n -> gcol = (n>>3)*512 + u0 + (n&7)
  __shared__ alignas(16) short Wlds[24576];            // 48 KB
  __shared__ alignas(16) unsigned short hstg[1024];    // 2 KB: per-wave 16x8 h tile

  const int tid  = threadIdx.x;
  const int lane = tid & 63;
  const int wv   = tid >> 6;
  const int u0   = blockIdx.x * 8;               // this WG's hidden units u0..u0+7

  for (int q = tid; q < 3072; q += NTHR) {
    int lq = q & 63;
    int kkn = q >> 6;                            // 0..47
    int nt = (kkn >= 24) ? 1 : 0;
    int kk = kkn - nt * 24;
    int kbase = kk * 32 + ((lq >> 4) << 3);
    int nn = (nt << 4) + (lq & 15);
    int gcol = ((nn >> 3) << 9) + u0 + (nn & 7); // gate g -> cols g*512 + unit
    short8 v;
#pragma unroll
    for (int j = 0; j < 8; ++j)
      v[j] = (short)f2bf(Wk[(size_t)(kbase + j) * GCOLS + gcol]);
    *(short8*)&Wlds[q * 8] = v;
  }

  // MFMA geometry: wave wv owns batches wv*16..+15; 2 N-tiles (32 gate cols).
  const int n   = lane & 15;                     // C col: gate pair + unit
  const int q4  = lane >> 4;                     // row quarter
  const int bb  = wv * 16 + n;                   // A-row (batch) this lane loads
  const int kq  = q4 << 3;                       // k sub-offset 0/8/16/24
  const int un  = n & 7;                         // unit within WG
  const bool lo = (n < 8);                       // lanes holding gates (i,f); hi = (j,o)

  // per-lane constants
  float bias_g[4];
#pragma unroll
  for (int g = 0; g < 4; ++g) bias_g[g] = bias[g * HID + u0 + un];
  int nw_r[4];
#pragma unroll
  for (int r = 0; r < 4; ++r) nw_r[r] = num_words[wv * 16 + q4 * 4 + r];

  float c_r[4] = {0.f, 0.f, 0.f, 0.f};
  float h_r[4] = {0.f, 0.f, 0.f, 0.f};

  unsigned* myflag = flags + ((blockIdx.x << 2) + wv) * 32;     // this wave's flag
  const unsigned* fp = flags + ((lane << 2) + wv) * 32;         // lane l polls WG l, wave wv

  unsigned short* hb[2] = {hb0, hb1};

  // ---- x prefetch registers ----
  float4 pfw[16];            // has_xb==0: raw fp32 embedding row slice
  uint4  pfx[8];             // has_xb==1: bf16 xb row slice
  auto PREFETCH = [&](int tt) {
    if (has_xb) {
      const unsigned short* xrow = xb + ((size_t)tt * BATCH + bb) * EDIM + kq;
#pragma unroll
      for (int kk = 0; kk < 8; ++kk)
        pfx[kk] = *(const uint4*)(xrow + kk * 32);
    } else {
      int wi = widx[bb * TSTEPS + tt];
      const float* er = Wemb + (size_t)wi * EDIM + kq;
#pragma unroll
      for (int kk = 0; kk < 8; ++kk) {
        pfw[2 * kk]     = *(const float4*)(er + kk * 32);
        pfw[2 * kk + 1] = *(const float4*)(er + kk * 32 + 4);
      }
    }
  };
  PREFETCH(0);

  __syncthreads();                               // Wlds ready (setup only)

  for (int t = 0; t < TSTEPS; ++t) {
    f32x4 acc0 = {0.f, 0.f, 0.f, 0.f};
    f32x4 acc1 = {0.f, 0.f, 0.f, 0.f};
    uint4 av[16];

    // ---- 1) poll producers, then immediately issue h-loads (overlap below) ----
    if (t > 0) {
      const unsigned tgt = (unsigned)t;
      for (;;) {
        unsigned v;
        asm volatile("global_load_dword %0, %1, off sc0 sc1\n\t"
                     "s_waitcnt vmcnt(0)" : "=v"(v) : "v"(fp));
        if (__ballot(v >= tgt) == ~0ull) break;
      }
      const unsigned short* hr = hb[t & 1] + bb * HID + kq;
#pragma unroll
      for (int kk = 0; kk < 16; ++kk)
        asm volatile("global_load_dwordx4 %0, %1, off sc0 sc1"
                     : "=v"(av[kk]) : "v"(hr + kk * 32));
    }

    // ---- 2) x part from PREFETCHED registers (VALU+MFMA overlaps h RT) ----
#pragma unroll
    for (int kk = 0; kk < 8; ++kk) {
      short8 a;
      if (has_xb) {
        a = __builtin_bit_cast(short8, pfx[kk]);
      } else {
        float4 f0 = pfw[2 * kk], f1 = pfw[2 * kk + 1];
        a[0] = (short)f2bf(f0.x); a[1] = (short)f2bf(f0.y);
        a[2] = (short)f2bf(f0.z); a[3] = (short)f2bf(f0.w);
        a[4] = (short)f2bf(f1.x); a[5] = (short)f2bf(f1.y);
        a[6] = (short)f2bf(f1.z); a[7] = (short)f2bf(f1.w);
      }
      short8 w0 = *(const short8*)&Wlds[((kk)      * 64 + lane) * 8];
      short8 w1 = *(const short8*)&Wlds[((24 + kk) * 64 + lane) * 8];
      acc0 = __builtin_amdgcn_mfma_f32_16x16x32_bf16(a, w0, acc0, 0, 0, 0);
      acc1 = __builtin_amdgcn_mfma_f32_16x16x32_bf16(a, w1, acc1, 0, 0, 0);
    }

    // ---- 3) drain h, h-MFMAs ----
    if (t > 0) {
      asm volatile("s_waitcnt vmcnt(0)" ::: "memory");
      __builtin_amdgcn_sched_barrier(0);         // keep h-MFMAs below the drain
#pragma unroll
      for (int kk = 0; kk < 16; ++kk) {
        short8 a  = __builtin_bit_cast(short8, av[kk]);
        short8 w0 = *(const short8*)&Wlds[((8 + kk)  * 64 + lane) * 8];
        short8 w1 = *(const short8*)&Wlds[((32 + kk) * 64 + lane) * 8];
        acc0 = __builtin_amdgcn_mfma_f32_16x16x32_bf16(a, w0, acc0, 0, 0, 0);
        acc1 = __builtin_amdgcn_mfma_f32_16x16x32_bf16(a, w1, acc1, 0, 0, 0);
      }
    }
    // (t==0: h_0 = 0 contributes nothing -- skip poll and h part)

    // ---- 4) in-wave epilogue: gates (i,j) in acc0 lanes n/n+8, (f,o) in acc1 ----
#pragma unroll
    for (int r = 0; r < 4; ++r) {
      float a0o = acc0[r], a1o = acc1[r];
      float a0x = __shfl_xor(a0o, 8);
      float a1x = __shfl_xor(a1o, 8);
      float gi = lo ? a0o : a0x;
      float gj = lo ? a0x : a0o;
      float gf = lo ? a1o : a1x;
      float go = lo ? a1x : a1o;
      lstm_cell(gi + bias_g[0], gj + bias_g[1], gf + bias_g[2], go + bias_g[3],
                t, nw_r[r], c_r[r], h_r[r]);
    }

    // ---- 5) publish h(t+1): pack via wave-local LDS, coalesced dword stores;
    //         then issue x(t+1) prefetch; counted vmcnt retires the stores while
    //         the gather loads stay in flight; finally post the wave flag. ----
    if (t + 1 < TSTEPS) {
      unsigned short* hw = hb[(t + 1) & 1];
      if (lo) {                                  // 8 units x 4 rows per lane group
#pragma unroll
        for (int r = 0; r < 4; ++r)
          hstg[wv * 256 + (q4 * 4 + r) * 8 + un] = f2bf(h_r[r]);
      }
      asm volatile("s_waitcnt lgkmcnt(0)" ::: "memory");  // wave-local visibility
      {
        // 64 lanes x 1 dword = 16 rows x 8 units, one coalesced 256B transaction
        int row = lane >> 2, p = lane & 3;
        unsigned hv = *(const unsigned*)&hstg[wv * 256 + row * 8 + p * 2];
        unsigned* dst = (unsigned*)(hw + (size_t)(wv * 16 + row) * HID + u0) + p;
        asm volatile("global_store_dword %0, %1, off sc0 sc1"
                     :: "v"(dst), "v"(hv) : "memory");
      }
      PREFETCH(t + 1);                           // issued AFTER the store
      if (has_xb)                                // store = oldest outstanding op:
        asm volatile("s_waitcnt vmcnt(8)" ::: "memory");   // 8 loads after it
      else
        asm volatile("s_waitcnt vmcnt(16)" ::: "memory");  // 16 loads after it
      if (lane == 0) {
        unsigned fv = (unsigned)(t + 1);
        asm volatile("global_store_dword %0, %1, off sc0 sc1"
                     :: "v"(myflag), "v"(fv) : "memory");
      }
    }
  }

  // ---- final state: out[0][b][h]=c, out[1][b][h]=h ----
  if (lo) {
#pragma unroll
    for (int r = 0; r < 4; ++r) {
      int b = wv * 16 + q4 * 4 + r;
      out[b * HID + u0 + un]                   = c_r[r];
      out[BATCH * HID + b * HID + u0 + un]     = h_r[r];
    }
  }
}

extern "C" void kernel_launch(void* const* d_in, const int* in_sizes, int n_in,
                              void* d_out, int out_size, void* d_ws, size_t ws_size,
                              hipStream_t stream) {
  const int*   widx = (const int*)d_in[0];
  const int*   nw   = (const int*)d_in[1];
  const float* Wemb = (const float*)d_in[2];
  const float* Wk   = (const float*)d_in[3];
  const float* bias = (const float*)d_in[4];
  float* out = (float*)d_out;
  char* ws = (char*)d_ws;

  unsigned* flags       = (unsigned*)(ws + 256);
  unsigned short* hb0   = (unsigned short*)(ws + 33280);
  unsigned short* hb1   = (unsigned short*)(ws + 98816);
  unsigned short* xb    = (unsigned short*)(ws + 164352);

  size_t need = 164352ull + (size_t)TSTEPS * BATCH * EDIM * 2;
  int has_xb = (ws_size >= need) ? 1 : 0;

  const int init_words = 164352 / 4;  // flags + both h buffers
  init_ws<<<(init_words + 255) / 256, 256, 0, stream>>>((unsigned*)ws, init_words);
  if (has_xb)
    embed_k<<<TSTEPS * BATCH, 64, 0, stream>>>(widx, Wemb, xb);

  void* args[] = {(void*)&nw, (void*)&widx, (void*)&Wemb, (void*)&Wk, (void*)&bias,
                  (void*)&xb, (void*)&hb0, (void*)&hb1, (void*)&flags,
                  (void*)&out, (void*)&has_xb};
  (void)hipLaunchCooperativeKernel((void*)lstm_persist, dim3(NWG), dim3(NTHR), args, 0, stream);
}